// Round 14
// baseline (185.470 us; speedup 1.0000x reference)
//
#include <hip/hip_runtime.h>
#include <hip/hip_bf16.h>

#define SEQ   2048
#define EMB   1024
#define NHEAD 16
#define DHEAD 64
#define BATCH 2
#define MTOT  (BATCH*SEQ)   // 4096
#define QT    128           // queries per attention block
#define KT    64            // keys per tile
#define NTILE (SEQ/KT)      // 32

typedef __attribute__((ext_vector_type(8))) short s8v;   // 8 bf16 (4 VGPRs)
typedef __attribute__((ext_vector_type(4))) short s4v;   // 4 bf16 (8 B)
typedef __attribute__((ext_vector_type(4))) float f4v;   // mfma accum

__device__ __forceinline__ short f2b(float f) {
    union { float fl; unsigned u; } v; v.fl = f;
    unsigned u = v.u;
    u = (u + 0x7fffu + ((u >> 16) & 1u)) >> 16;   // round-to-nearest-even
    return (short)u;
}
// packed fp32x2 -> bf16x2 (v_cvt_pk_bf16_f32); rounded values also feed the
// softmax denominator (consistency => rounding-mode-agnostic).
__device__ __forceinline__ unsigned pk2(float a, float b) {
    union { __hip_bfloat162 h; unsigned u; } c;
    c.h = __float22bfloat162_rn(float2{a, b});
    return c.u;
}

#if __has_builtin(__builtin_amdgcn_exp2f)
__device__ __forceinline__ float exp2_fast(float x) { return __builtin_amdgcn_exp2f(x); }
#else
__device__ __forceinline__ float exp2_fast(float x) { return exp2f(x); }
#endif

// gfx950 cross-lane half-swaps: dst upper part <-> src lower part.
__device__ __forceinline__ void pl32swap(unsigned &a, unsigned &b) {
    asm("v_permlane32_swap_b32 %0, %1" : "+v"(a), "+v"(b));
}
__device__ __forceinline__ void pl16swap(unsigned &a, unsigned &b) {
    asm("v_permlane16_swap_b32 %0, %1" : "+v"(a), "+v"(b));
}

// Raw workgroup barrier: LDS-visibility only (lgkmcnt drain), does NOT drain
// vmcnt — outstanding global prefetch loads stay in flight across it.
__device__ __forceinline__ void bar_lds() {
    asm volatile("s_waitcnt lgkmcnt(0)\n\ts_barrier" ::: "memory");
}

// async global->LDS DMA, 16 B/lane; LDS dest = wave-uniform base + lane*16.
__device__ __forceinline__ void gl_lds16(const short* g, short* l) {
    __builtin_amdgcn_global_load_lds(
        (const __attribute__((address_space(1))) void*)g,
        (__attribute__((address_space(3))) void*)l, 16, 0, 0);
}

// ---- fp32 -> bf16 convert + chunk swizzle ----
// Output rows are 1024 bf16 = 16 aligned 128B groups of 8 16B-chunks.
// Chunk c of row r is stored at slot (c&~7) | ((c&7) ^ (r&7)) so that
// global_load_lds' contiguous DMA lands a bank-uniform LDS image.
__global__ __launch_bounds__(256)
void cvt_swz(const float* __restrict__ s0, const float* __restrict__ s1,
             const float* __restrict__ s2, const float* __restrict__ s3,
             const float* __restrict__ s4,
             short* __restrict__ d0, short* __restrict__ d1,
             short* __restrict__ d2, short* __restrict__ d3,
             short* __restrict__ d4)
{
    const int seg = blockIdx.y;
    const float* s = seg == 0 ? s0 : seg == 1 ? s1 : seg == 2 ? s2 : seg == 3 ? s3 : s4;
    short*       d = seg == 0 ? d0 : seg == 1 ? d1 : seg == 2 ? d2 : seg == 3 ? d3 : d4;
    const int nchunk = (seg == 0 ? MTOT * EMB : EMB * EMB) / 8;   // 16B chunks
    const int stride = gridDim.x * 256;
    for (int i = blockIdx.x * 256 + threadIdx.x; i < nchunk; i += stride) {
        const int row = i >> 7;         // 128 chunks per 1024-col row
        const int c   = i & 127;
        const float4 v0 = *(const float4*)(s + (size_t)i * 8);
        const float4 v1 = *(const float4*)(s + (size_t)i * 8 + 4);
        union { unsigned uu[4]; s8v s8; } o;
        o.uu[0] = pk2(v0.x, v0.y);
        o.uu[1] = pk2(v0.z, v0.w);
        o.uu[2] = pk2(v1.x, v1.y);
        o.uu[3] = pk2(v1.z, v1.w);
        const int cp = (c & ~7) | ((c & 7) ^ (row & 7));
        *(s8v*)(d + (size_t)row * EMB + cp * 8) = o.s8;
    }
}

// NT GEMM via global_load_lds (m97 structure): C = A*W^T + bias.
// A, W are bf16 with swizzled 16B chunks (see cvt_swz). LDS rows unpadded
// (128 B); frag reads address slot (kk*4+quad)^(l16&7) -> bank-uniform.
// FUSED3: 3 matrices (QKV); mat 2 writes V transposed per-head [b][h][d][s].
// mat 0 (Q) output is prescaled by 0.125*log2(e) so attention uses exp2.
// 2D XCD region swizzle (r10). Out-proj keeps r11's dbuf 1-barrier body.
template<int NT, bool FUSED3>
__global__ __launch_bounds__(256, 3)
void gemm_bb3(const short* __restrict__ A,
              const short* __restrict__ W0, const short* __restrict__ W1, const short* __restrict__ W2,
              const float* __restrict__ B0, const float* __restrict__ B1, const float* __restrict__ B2,
              void* __restrict__ C0, void* __restrict__ C1, void* __restrict__ C2)
{
    constexpr int JN = NT / 32;
    const int K = EMB, N = EMB;
    const int ntiles = EMB / NT;

    // ---- 2D XCD region swizzle (bijective remap of the tile grid) ----
    const int L   = blockIdx.x + gridDim.x * blockIdx.y;   // dispatch order
    const int xcd = L & 7;
    const int s   = L >> 3;                                // per-XCD sequence
    constexpr int XW = FUSED3 ? 12 : 8;                    // x-tiles per region
    const int x = (xcd & 1) * XW + s / 8;                  // y-fastest order
    const int y = (xcd >> 1) * 8 + (s & 7);

    const int mat = x / ntiles;
    const int n0  = (x % ntiles) * NT;
    const int m0  = y * 128;
    const short* W  = (mat == 0) ? W0 : (mat == 1 ? W1 : W2);
    const float* Bi = (mat == 0) ? B0 : (mat == 1 ? B1 : B2);
    void*        C  = (mat == 0) ? C0 : (mat == 1 ? C1 : C2);
    const float qscale = (FUSED3 && mat == 0) ? 0.18033688f : 1.0f;  // 1/8*log2e

    const int tid  = threadIdx.x;
    const int lane = tid & 63;
    const int wave = tid >> 6;
    const int quad = lane >> 4;
    const int l16  = lane & 15;
    const int l8   = l16 & 7;
    const int wm   = wave >> 1;
    const int wn   = wave & 1;

    f4v acc[4][JN] = {};

    const int srow = lane >> 3;    // staging row within 8-row group
    const int scol = (lane & 7) * 8;

    if constexpr (FUSED3) {
        // ---- 2-barrier single-buffer body (R3-proven) ----
        __shared__ __align__(16) short As[128 * 64];
        __shared__ __align__(16) short Ws[NT * 64];

        for (int k0 = 0; k0 < K; k0 += 64) {
            #pragma unroll
            for (int p = 0; p < 4; ++p) {
                const int rbase = wave * 32 + p * 8;
                gl_lds16(A + (size_t)(m0 + rbase + srow) * K + k0 + scol,
                         As + rbase * 64);
            }
            #pragma unroll
            for (int p = 0; p < NT / 32; ++p) {
                const int rbase = wave * (NT / 4) + p * 8;
                gl_lds16(W + (size_t)(n0 + rbase + srow) * K + k0 + scol,
                         Ws + rbase * 64);
            }
            __syncthreads();   // drains the DMA (vmcnt) + barrier

            #pragma unroll
            for (int kk = 0; kk < 2; ++kk) {
                const int slot = ((kk * 4 + quad) ^ l8) * 8;
                s8v af[4], wf[JN];
                #pragma unroll
                for (int i = 0; i < 4; ++i)
                    af[i] = *(const s8v*)(As + (wm * 64 + i * 16 + l16) * 64 + slot);
                #pragma unroll
                for (int j = 0; j < JN; ++j)
                    wf[j] = *(const s8v*)(Ws + (wn * (NT / 2) + j * 16 + l16) * 64 + slot);
                #pragma unroll
                for (int i = 0; i < 4; ++i)
                    #pragma unroll
                    for (int j = 0; j < JN; ++j)
                        acc[i][j] = __builtin_amdgcn_mfma_f32_16x16x32_bf16(
                            af[i], wf[j], acc[i][j], 0, 0, 0);
            }
            __syncthreads();   // all waves done reading before next overwrite
        }

        // C/D layout: col = lane&15 (n), row = quad*4+reg (m)  [m89-verified]
        #pragma unroll
        for (int j = 0; j < JN; ++j) {
            const int n = n0 + wn * (NT / 2) + j * 16 + l16;
            const float bv = Bi[n];
            #pragma unroll
            for (int i = 0; i < 4; ++i) {
                const int mb = m0 + wm * 64 + i * 16 + quad * 4;
                if (mat == 2) {
                    const int bb = mb >> 11, ss = mb & 2047;
                    s4v ov;
                    #pragma unroll
                    for (int rr = 0; rr < 4; ++rr) ov[rr] = f2b(acc[i][j][rr] + bv);
                    *(s4v*)((short*)C + ((size_t)(bb * 1024 + n)) * SEQ + ss) = ov;
                } else {
                    #pragma unroll
                    for (int rr = 0; rr < 4; ++rr)
                        ((short*)C)[(size_t)(mb + rr) * N + n] = f2b((acc[i][j][rr] + bv) * qscale);
                }
            }
        }
    } else {
        // ---- r11: dbuf + 1-barrier body (attn_mfma7 structure) ----
        __shared__ __align__(16) short As[2][128 * 64];
        __shared__ __align__(16) short Ws[2][NT * 64];

        // prologue: issue DMA for K-step 0 into buf 0
        #pragma unroll
        for (int p = 0; p < 4; ++p) {
            const int rbase = wave * 32 + p * 8;
            gl_lds16(A + (size_t)(m0 + rbase + srow) * K + scol, As[0] + rbase * 64);
        }
        #pragma unroll
        for (int p = 0; p < NT / 32; ++p) {
            const int rbase = wave * (NT / 4) + p * 8;
            gl_lds16(W + (size_t)(n0 + rbase + srow) * K + scol, Ws[0] + rbase * 64);
        }

        for (int t = 0; t < K / 64; ++t) {
            const int buf = t & 1;
            __syncthreads();   // vmcnt(0)+barrier: tile t landed everywhere;
                               // compute(t-1) done everywhere -> buf^1 free
            if (t + 1 < K / 64) {
                const int k1 = (t + 1) * 64;
                #pragma unroll
                for (int p = 0; p < 4; ++p) {
                    const int rbase = wave * 32 + p * 8;
                    gl_lds16(A + (size_t)(m0 + rbase + srow) * K + k1 + scol,
                             As[buf ^ 1] + rbase * 64);
                }
                #pragma unroll
                for (int p = 0; p < NT / 32; ++p) {
                    const int rbase = wave * (NT / 4) + p * 8;
                    gl_lds16(W + (size_t)(n0 + rbase + srow) * K + k1 + scol,
                             Ws[buf ^ 1] + rbase * 64);
                }
            }
            const short* AsB = As[buf];
            const short* WsB = Ws[buf];

            #pragma unroll
            for (int kk = 0; kk < 2; ++kk) {
                const int slot = ((kk * 4 + quad) ^ l8) * 8;
                s8v af[4], wf[JN];
                #pragma unroll
                for (int i = 0; i < 4; ++i)
                    af[i] = *(const s8v*)(AsB + (wm * 64 + i * 16 + l16) * 64 + slot);
                #pragma unroll
                for (int j = 0; j < JN; ++j)
                    wf[j] = *(const s8v*)(WsB + (wn * (NT / 2) + j * 16 + l16) * 64 + slot);
                #pragma unroll
                for (int i = 0; i < 4; ++i)
                    #pragma unroll
                    for (int j = 0; j < JN; ++j)
                        acc[i][j] = __builtin_amdgcn_mfma_f32_16x16x32_bf16(
                            af[i], wf[j], acc[i][j], 0, 0, 0);
            }
        }

        // ---- out-proj epilogue (R3-proven): fp32, sector-aligned ----
        #pragma unroll
        for (int j = 0; j < JN; ++j) {
            const int n = n0 + wn * (NT / 2) + j * 16 + l16;
            const float bv = Bi[n];
            #pragma unroll
            for (int i = 0; i < 4; ++i) {
                const int mb = m0 + wm * 64 + i * 16 + quad * 4;
                #pragma unroll
                for (int rr = 0; rr < 4; ++rr)
                    ((float*)C)[(size_t)(mb + rr) * N + n] = acc[i][j][rr] + bv;
            }
        }
    }
}

// MFMA flash attention v11 (r14): v7 + T4 counted-vmcnt barriers.
// v7's __syncthreads drained vmcnt(0) every tile: DMA(t+1) had only
// compute(t) to complete -> every wave stalled at every barrier on the
// freshest loads. Now: 4-deep LDS buffers, prefetch depth 2, and
// s_waitcnt vmcnt(4) (NOT 0) before each barrier — retires this wave's
// tile-t loads (the barrier then guarantees all other waves did the same
// for their slices), leaves tiles t+1/t+2 in flight across the barrier.
// Each tile's DMA gets TWO compute phases of cover. Buffer safety (mod 4):
// DMA(t+2) writes buf[(t+2)&3]; live readers are compute(t) [t&3] and
// compute(t-1) [(t-1)&3], both distinct; compute(t-2) [same buf] finished
// before barrier(t-1) by program order. Tail: vmcnt(2) at t=30, vmcnt(0)
// at t=31. LDS 64 KB, 2 blocks/CU (128 <= 160). Rest identical to v7.
__global__ __launch_bounds__(512, 4)
void attn_mfma11(const short* Q, const short* __restrict__ Kg,
                 const short* __restrict__ Vt, short* O)
{
    // dispatch i -> XCD i&7 (round-robin). Give each XCD 4 (b,h) combos.
    const int i    = blockIdx.x;          // 512 blocks
    const int xcd  = i & 7;
    const int slot = i >> 3;              // 0..63
    const int combo = xcd * 4 + (slot >> 4);   // (b,h) 0..31
    const int qb = slot & 15;                  // 16 q-blocks per (b,h)
    const int h  = combo & 15;
    const int b  = combo >> 4;
    const int q0 = qb * QT;

    const int tid  = threadIdx.x;
    const int lane = tid & 63;
    const int wave = tid >> 6;            // 0..7
    const int quad = lane >> 4;
    const int l16  = lane & 15;
    const int l8   = l16 & 7;

    __shared__ __align__(16) short Ks[4][64 * 64];   // [key][d] swizzled image
    __shared__ __align__(16) short Vs[4][64 * 64];   // [d][key] swizzled image
    constexpr int BUFS = 64 * 64;

    // Q B-frags (prescaled by 0.125*log2e): wave handles 16 q-rows
    s8v qf[2];
    #pragma unroll
    for (int kk = 0; kk < 2; ++kk)
        qf[kk] = *(const s8v*)(Q + (size_t)(b * SEQ + q0 + wave * 16 + l16) * EMB
                                 + h * DHEAD + kk * 32 + quad * 8);

    f4v oacc[4] = {};   // [j: d-block] -> O^T[d][q]
    f4v sacc    = {};   // ones-MFMA row sums (col = q, all rows equal)
    s8v onef;
    #pragma unroll
    for (int e = 0; e < 8; ++e) onef[e] = (short)0x3F80;   // bf16 1.0

    // ---- DMA staging setup: lane (r,c) covers row r, physical chunk c ----
    const int r = lane >> 3, c = lane & 7;
    const int sc8 = (c ^ r) * 8;               // pre-swizzled source chunk
    const bool isK = wave < 4;
    const int wrow = (wave & 3) * 16;          // 16 rows per stager wave
    const size_t kbase = (size_t)(b * SEQ) * EMB + h * DHEAD;
    const size_t vbase = (size_t)((b * NHEAD + h) * DHEAD) * SEQ;
    // per-lane global source for tile 0
    const short* gsrc = isK ? Kg + kbase + (size_t)(wrow + r) * EMB + sc8
                            : Vt + vbase + (size_t)(wrow + r) * SEQ + sc8;
    const size_t gstep8 = isK ? (size_t)8 * EMB : (size_t)8 * SEQ;  // +8 rows
    const size_t tstep  = isK ? (size_t)KT * EMB : (size_t)KT;      // +1 tile
    short* const lbase  = (isK ? (short*)Ks : (short*)Vs) + wrow * 64;

    // prologue: issue DMA for tiles 0 and 1 into bufs 0 and 1
    gl_lds16(gsrc,          lbase);
    gl_lds16(gsrc + gstep8, lbase + 8 * 64);
    {
        const short* g1 = gsrc + tstep;
        gl_lds16(g1,          lbase + BUFS);
        gl_lds16(g1 + gstep8, lbase + BUFS + 8 * 64);
    }
    const short* gnext = gsrc + 2 * tstep;   // tile 2

    for (int t = 0; t < NTILE; ++t) {
        if (t + 2 < NTILE) {
            // issue DMA(t+2) BEFORE the barrier; it stays in flight across
            // the barrier and all of compute(t) and compute(t+1).
            short* ldst = lbase + ((t + 2) & 3) * BUFS;
            gl_lds16(gnext,          ldst);
            gl_lds16(gnext + gstep8, ldst + 8 * 64);
            gnext += tstep;
            // retire tile t's loads (oldest); keep t+1, t+2 in flight
            asm volatile("s_waitcnt vmcnt(4) lgkmcnt(0)\n\ts_barrier" ::: "memory");
        } else if (t == NTILE - 2) {
            asm volatile("s_waitcnt vmcnt(2) lgkmcnt(0)\n\ts_barrier" ::: "memory");
        } else {   // t == NTILE-1
            asm volatile("s_waitcnt vmcnt(0) lgkmcnt(0)\n\ts_barrier" ::: "memory");
        }
        const short* KsB = Ks[t & 3];
        const short* VsB = Vs[t & 3];

        // ---- S^T[key][q] = K · Q^T (already in log2 domain) ----
        f4v sc[4] = {};
        #pragma unroll
        for (int kk = 0; kk < 2; ++kk) {
            const int ko = ((kk * 4 + quad) ^ l8) * 8;
            s8v kf[4];
            #pragma unroll
            for (int j = 0; j < 4; ++j)
                kf[j] = *(const s8v*)(KsB + (j * 16 + l16) * 64 + ko);
            #pragma unroll
            for (int j = 0; j < 4; ++j)
                sc[j] = __builtin_amdgcn_mfma_f32_16x16x32_bf16(
                    kf[j], qf[kk], sc[j], 0, 0, 0);
        }

        // ---- p = 2^s, pack to bf16 pairs ----
        unsigned u[4][2];
        #pragma unroll
        for (int j = 0; j < 4; ++j) {
            u[j][0] = pk2(exp2_fast(sc[j][0]), exp2_fast(sc[j][1]));
            u[j][1] = pk2(exp2_fast(sc[j][2]), exp2_fast(sc[j][3]));
        }

        // ---- in-register all-to-all over lane bits 4/5 ----
        #pragma unroll
        for (int r2 = 0; r2 < 2; ++r2) {
            pl32swap(u[0][r2], u[1][r2]);   // stage A: b5' = j&1
            pl32swap(u[2][r2], u[3][r2]);
            pl16swap(u[0][r2], u[1][r2]);   // stage B: b4' = orig b5
            pl16swap(u[2][r2], u[3][r2]);
        }
        union { unsigned uu[4]; s8v s; } pfa, pfb;
        pfa.uu[0] = u[0][0]; pfa.uu[1] = u[0][1]; pfa.uu[2] = u[1][0]; pfa.uu[3] = u[1][1];
        pfb.uu[0] = u[2][0]; pfb.uu[1] = u[2][1]; pfb.uu[2] = u[3][0]; pfb.uu[3] = u[3][1];

        // ---- O^T[d][q] += V^T[d][key] · P^T ; row sums via ones-MFMA ----
        #pragma unroll
        for (int kk = 0; kk < 2; ++kk) {
            const s8v pf = kk ? pfb.s : pfa.s;
            sacc = __builtin_amdgcn_mfma_f32_16x16x32_bf16(onef, pf, sacc, 0, 0, 0);
            const int ko = ((kk * 4 + quad) ^ l8) * 8;
            #pragma unroll
            for (int j = 0; j < 4; ++j) {
                const s8v vf = *(const s8v*)(VsB + (j * 16 + l16) * 64 + ko);
                oacc[j] = __builtin_amdgcn_mfma_f32_16x16x32_bf16(
                    vf, pf, oacc[j], 0, 0, 0);
            }
        }
    }

    // ---- denominator: every row of sacc holds the full sum for col q ----
    const float inv = 1.0f / sacc[0];

    __syncthreads();   // everyone done with K/V LDS; reuse Ks[0..1] as Os
    short* Os = (short*)Ks;   // 128 rows x 64 shorts = 16 KB
    #pragma unroll
    for (int j = 0; j < 4; ++j) {
        union { unsigned uu[2]; s4v s; } ov;
        ov.uu[0] = pk2(oacc[j][0] * inv, oacc[j][1] * inv);
        ov.uu[1] = pk2(oacc[j][2] * inv, oacc[j][3] * inv);
        const int pc = ((j * 2 + (quad >> 1)) ^ l8) * 8 + (quad & 1) * 4;
        *(s4v*)(Os + (wave * 16 + l16) * 64 + pc) = ov.s;
    }
    bar_lds();

    // ---- coalesced store: LDS swizzle cancels the output chunk swizzle ----
    const int row = tid >> 2;            // 0..127
    const int cb  = (tid & 3) * 2;       // two physical chunks per thread
    #pragma unroll
    for (int c4 = 0; c4 < 2; ++c4) {
        const int pcc = cb + c4;
        const s8v tt = *(const s8v*)(Os + row * 64 + pcc * 8);
        *(s8v*)(O + (size_t)(b * SEQ + q0 + row) * EMB + h * DHEAD + pcc * 8) = tt;
    }
}

extern "C" void kernel_launch(void* const* d_in, const int* in_sizes, int n_in,
                              void* d_out, int out_size, void* d_ws, size_t ws_size,
                              hipStream_t stream)
{
    const float* x  = (const float*)d_in[0];
    const float* Wq = (const float*)d_in[1];
    const float* bq = (const float*)d_in[2];
    const float* Wk = (const float*)d_in[3];
    const float* bk = (const float*)d_in[4];
    const float* Wv = (const float*)d_in[5];
    const float* bv = (const float*)d_in[6];
    const float* Wo = (const float*)d_in[7];
    const float* bo = (const float*)d_in[8];
    float* out = (float*)d_out;   // fp32 output

    short* xb  = (short*)d_ws;                       // 4096x1024 bf16, swizzled
    short* Wqb = xb  + (size_t)MTOT * EMB;           // swizzled
    short* Wkb = Wqb + (size_t)EMB * EMB;
    short* Wvb = Wkb + (size_t)EMB * EMB;
    short* Wob = Wvb + (size_t)EMB * EMB;
    short* Qw  = Wob + (size_t)EMB * EMB;            // [token][1024] (Q: plain;
                                                     //  then O: swizzled)
    short* Kw  = Qw  + (size_t)MTOT * EMB;           // [token][1024] plain
    short* Vtw = Kw  + (size_t)MTOT * EMB;           // [b][h][d][s] plain

    cvt_swz<<<dim3(512, 5), 256, 0, stream>>>(x, Wq, Wk, Wv, Wo,
                                              xb, Wqb, Wkb, Wvb, Wob);

    gemm_bb3<128, true><<<dim3(24, 32), 256, 0, stream>>>(
        xb, Wqb, Wkb, Wvb, bq, bk, bv, Qw, Kw, Vtw);

    attn_mfma11<<<dim3(BATCH * NHEAD * (SEQ / QT)), 512, 0, stream>>>(Qw, Kw, Vtw, Qw);

    gemm_bb3<64, false><<<dim3(16, 32), 256, 0, stream>>>(
        Qw, Wob, Wob, Wob, bo, bo, bo, out, out, out);
}

// Round 15
// 179.211 us; speedup vs baseline: 1.0349x; 1.0349x over previous
//
#include <hip/hip_runtime.h>
#include <hip/hip_bf16.h>

#define SEQ   2048
#define EMB   1024
#define NHEAD 16
#define DHEAD 64
#define BATCH 2
#define MTOT  (BATCH*SEQ)   // 4096
#define QT    128           // queries per attention block
#define KT    64            // keys per tile
#define NTILE (SEQ/KT)      // 32

typedef __attribute__((ext_vector_type(8))) short s8v;   // 8 bf16 (4 VGPRs)
typedef __attribute__((ext_vector_type(4))) short s4v;   // 4 bf16 (8 B)
typedef __attribute__((ext_vector_type(4))) float f4v;   // mfma accum

__device__ __forceinline__ short f2b(float f) {
    union { float fl; unsigned u; } v; v.fl = f;
    unsigned u = v.u;
    u = (u + 0x7fffu + ((u >> 16) & 1u)) >> 16;   // round-to-nearest-even
    return (short)u;
}
// packed fp32x2 -> bf16x2 (v_cvt_pk_bf16_f32); rounded values also feed the
// softmax denominator (consistency => rounding-mode-agnostic).
__device__ __forceinline__ unsigned pk2(float a, float b) {
    union { __hip_bfloat162 h; unsigned u; } c;
    c.h = __float22bfloat162_rn(float2{a, b});
    return c.u;
}

#if __has_builtin(__builtin_amdgcn_exp2f)
__device__ __forceinline__ float exp2_fast(float x) { return __builtin_amdgcn_exp2f(x); }
#else
__device__ __forceinline__ float exp2_fast(float x) { return exp2f(x); }
#endif

// gfx950 cross-lane half-swaps: dst upper part <-> src lower part.
__device__ __forceinline__ void pl32swap(unsigned &a, unsigned &b) {
    asm("v_permlane32_swap_b32 %0, %1" : "+v"(a), "+v"(b));
}
__device__ __forceinline__ void pl16swap(unsigned &a, unsigned &b) {
    asm("v_permlane16_swap_b32 %0, %1" : "+v"(a), "+v"(b));
}

// Raw workgroup barrier: LDS-visibility only (lgkmcnt drain), does NOT drain
// vmcnt — outstanding global prefetch loads stay in flight across it.
__device__ __forceinline__ void bar_lds() {
    asm volatile("s_waitcnt lgkmcnt(0)\n\ts_barrier" ::: "memory");
}

// async global->LDS DMA, 16 B/lane; LDS dest = wave-uniform base + lane*16.
__device__ __forceinline__ void gl_lds16(const short* g, short* l) {
    __builtin_amdgcn_global_load_lds(
        (const __attribute__((address_space(1))) void*)g,
        (__attribute__((address_space(3))) void*)l, 16, 0, 0);
}

// ---- fp32 -> bf16 convert + chunk swizzle ----
// Output rows are 1024 bf16 = 16 aligned 128B groups of 8 16B-chunks.
// Chunk c of row r is stored at slot (c&~7) | ((c&7) ^ (r&7)) so that
// global_load_lds' contiguous DMA lands a bank-uniform LDS image.
// r11: rounding via v_cvt_pk_bf16_f32 (bit-identical RNE to f2b, half the VALU).
__global__ __launch_bounds__(256)
void cvt_swz(const float* __restrict__ s0, const float* __restrict__ s1,
             const float* __restrict__ s2, const float* __restrict__ s3,
             const float* __restrict__ s4,
             short* __restrict__ d0, short* __restrict__ d1,
             short* __restrict__ d2, short* __restrict__ d3,
             short* __restrict__ d4)
{
    const int seg = blockIdx.y;
    const float* s = seg == 0 ? s0 : seg == 1 ? s1 : seg == 2 ? s2 : seg == 3 ? s3 : s4;
    short*       d = seg == 0 ? d0 : seg == 1 ? d1 : seg == 2 ? d2 : seg == 3 ? d3 : d4;
    const int nchunk = (seg == 0 ? MTOT * EMB : EMB * EMB) / 8;   // 16B chunks
    const int stride = gridDim.x * 256;
    for (int i = blockIdx.x * 256 + threadIdx.x; i < nchunk; i += stride) {
        const int row = i >> 7;         // 128 chunks per 1024-col row
        const int c   = i & 127;
        const float4 v0 = *(const float4*)(s + (size_t)i * 8);
        const float4 v1 = *(const float4*)(s + (size_t)i * 8 + 4);
        union { unsigned uu[4]; s8v s8; } o;
        o.uu[0] = pk2(v0.x, v0.y);
        o.uu[1] = pk2(v0.z, v0.w);
        o.uu[2] = pk2(v1.x, v1.y);
        o.uu[3] = pk2(v1.z, v1.w);
        const int cp = (c & ~7) | ((c & 7) ^ (row & 7));
        *(s8v*)(d + (size_t)row * EMB + cp * 8) = o.s8;
    }
}

// NT GEMM via global_load_lds (m97 structure): C = A*W^T + bias.
// A, W are bf16 with swizzled 16B chunks (see cvt_swz). LDS rows unpadded
// (128 B); frag reads address slot (kk*4+quad)^(l16&7) -> bank-uniform.
// FUSED3: 3 matrices (QKV); mat 2 writes V transposed per-head [b][h][d][s].
// mat 0 (Q) output is prescaled by 0.125*log2(e) so attention uses exp2.
// 2D XCD region swizzle (r10). Out-proj keeps r11's dbuf 1-barrier body.
template<int NT, bool FUSED3>
__global__ __launch_bounds__(256, 3)
void gemm_bb3(const short* __restrict__ A,
              const short* __restrict__ W0, const short* __restrict__ W1, const short* __restrict__ W2,
              const float* __restrict__ B0, const float* __restrict__ B1, const float* __restrict__ B2,
              void* __restrict__ C0, void* __restrict__ C1, void* __restrict__ C2)
{
    constexpr int JN = NT / 32;
    const int K = EMB, N = EMB;
    const int ntiles = EMB / NT;

    // ---- 2D XCD region swizzle (bijective remap of the tile grid) ----
    const int L   = blockIdx.x + gridDim.x * blockIdx.y;   // dispatch order
    const int xcd = L & 7;
    const int s   = L >> 3;                                // per-XCD sequence
    constexpr int XW = FUSED3 ? 12 : 8;                    // x-tiles per region
    const int x = (xcd & 1) * XW + s / 8;                  // y-fastest order
    const int y = (xcd >> 1) * 8 + (s & 7);

    const int mat = x / ntiles;
    const int n0  = (x % ntiles) * NT;
    const int m0  = y * 128;
    const short* W  = (mat == 0) ? W0 : (mat == 1 ? W1 : W2);
    const float* Bi = (mat == 0) ? B0 : (mat == 1 ? B1 : B2);
    void*        C  = (mat == 0) ? C0 : (mat == 1 ? C1 : C2);
    const float qscale = (FUSED3 && mat == 0) ? 0.18033688f : 1.0f;  // 1/8*log2e

    const int tid  = threadIdx.x;
    const int lane = tid & 63;
    const int wave = tid >> 6;
    const int quad = lane >> 4;
    const int l16  = lane & 15;
    const int l8   = l16 & 7;
    const int wm   = wave >> 1;
    const int wn   = wave & 1;

    f4v acc[4][JN] = {};

    const int srow = lane >> 3;    // staging row within 8-row group
    const int scol = (lane & 7) * 8;

    if constexpr (FUSED3) {
        // ---- 2-barrier single-buffer body (R3-proven) ----
        __shared__ __align__(16) short As[128 * 64];
        __shared__ __align__(16) short Ws[NT * 64];

        for (int k0 = 0; k0 < K; k0 += 64) {
            #pragma unroll
            for (int p = 0; p < 4; ++p) {
                const int rbase = wave * 32 + p * 8;
                gl_lds16(A + (size_t)(m0 + rbase + srow) * K + k0 + scol,
                         As + rbase * 64);
            }
            #pragma unroll
            for (int p = 0; p < NT / 32; ++p) {
                const int rbase = wave * (NT / 4) + p * 8;
                gl_lds16(W + (size_t)(n0 + rbase + srow) * K + k0 + scol,
                         Ws + rbase * 64);
            }
            __syncthreads();   // drains the DMA (vmcnt) + barrier

            #pragma unroll
            for (int kk = 0; kk < 2; ++kk) {
                const int slot = ((kk * 4 + quad) ^ l8) * 8;
                s8v af[4], wf[JN];
                #pragma unroll
                for (int i = 0; i < 4; ++i)
                    af[i] = *(const s8v*)(As + (wm * 64 + i * 16 + l16) * 64 + slot);
                #pragma unroll
                for (int j = 0; j < JN; ++j)
                    wf[j] = *(const s8v*)(Ws + (wn * (NT / 2) + j * 16 + l16) * 64 + slot);
                #pragma unroll
                for (int i = 0; i < 4; ++i)
                    #pragma unroll
                    for (int j = 0; j < JN; ++j)
                        acc[i][j] = __builtin_amdgcn_mfma_f32_16x16x32_bf16(
                            af[i], wf[j], acc[i][j], 0, 0, 0);
            }
            __syncthreads();   // all waves done reading before next overwrite
        }

        // C/D layout: col = lane&15 (n), row = quad*4+reg (m)  [m89-verified]
        #pragma unroll
        for (int j = 0; j < JN; ++j) {
            const int n = n0 + wn * (NT / 2) + j * 16 + l16;
            const float bv = Bi[n];
            #pragma unroll
            for (int i = 0; i < 4; ++i) {
                const int mb = m0 + wm * 64 + i * 16 + quad * 4;
                if (mat == 2) {
                    const int bb = mb >> 11, ss = mb & 2047;
                    s4v ov;
                    #pragma unroll
                    for (int rr = 0; rr < 4; ++rr) ov[rr] = f2b(acc[i][j][rr] + bv);
                    *(s4v*)((short*)C + ((size_t)(bb * 1024 + n)) * SEQ + ss) = ov;
                } else {
                    #pragma unroll
                    for (int rr = 0; rr < 4; ++rr)
                        ((short*)C)[(size_t)(mb + rr) * N + n] = f2b((acc[i][j][rr] + bv) * qscale);
                }
            }
        }
    } else {
        // ---- r11: dbuf + 1-barrier body (attn_mfma7 structure) ----
        __shared__ __align__(16) short As[2][128 * 64];
        __shared__ __align__(16) short Ws[2][NT * 64];

        // prologue: issue DMA for K-step 0 into buf 0
        #pragma unroll
        for (int p = 0; p < 4; ++p) {
            const int rbase = wave * 32 + p * 8;
            gl_lds16(A + (size_t)(m0 + rbase + srow) * K + scol, As[0] + rbase * 64);
        }
        #pragma unroll
        for (int p = 0; p < NT / 32; ++p) {
            const int rbase = wave * (NT / 4) + p * 8;
            gl_lds16(W + (size_t)(n0 + rbase + srow) * K + scol, Ws[0] + rbase * 64);
        }

        for (int t = 0; t < K / 64; ++t) {
            const int buf = t & 1;
            __syncthreads();   // vmcnt(0)+barrier: tile t landed everywhere;
                               // compute(t-1) done everywhere -> buf^1 free
            if (t + 1 < K / 64) {
                const int k1 = (t + 1) * 64;
                #pragma unroll
                for (int p = 0; p < 4; ++p) {
                    const int rbase = wave * 32 + p * 8;
                    gl_lds16(A + (size_t)(m0 + rbase + srow) * K + k1 + scol,
                             As[buf ^ 1] + rbase * 64);
                }
                #pragma unroll
                for (int p = 0; p < NT / 32; ++p) {
                    const int rbase = wave * (NT / 4) + p * 8;
                    gl_lds16(W + (size_t)(n0 + rbase + srow) * K + k1 + scol,
                             Ws[buf ^ 1] + rbase * 64);
                }
            }
            const short* AsB = As[buf];
            const short* WsB = Ws[buf];

            #pragma unroll
            for (int kk = 0; kk < 2; ++kk) {
                const int slot = ((kk * 4 + quad) ^ l8) * 8;
                s8v af[4], wf[JN];
                #pragma unroll
                for (int i = 0; i < 4; ++i)
                    af[i] = *(const s8v*)(AsB + (wm * 64 + i * 16 + l16) * 64 + slot);
                #pragma unroll
                for (int j = 0; j < JN; ++j)
                    wf[j] = *(const s8v*)(WsB + (wn * (NT / 2) + j * 16 + l16) * 64 + slot);
                #pragma unroll
                for (int i = 0; i < 4; ++i)
                    #pragma unroll
                    for (int j = 0; j < JN; ++j)
                        acc[i][j] = __builtin_amdgcn_mfma_f32_16x16x32_bf16(
                            af[i], wf[j], acc[i][j], 0, 0, 0);
            }
        }

        // ---- out-proj epilogue (R3-proven): fp32, sector-aligned ----
        #pragma unroll
        for (int j = 0; j < JN; ++j) {
            const int n = n0 + wn * (NT / 2) + j * 16 + l16;
            const float bv = Bi[n];
            #pragma unroll
            for (int i = 0; i < 4; ++i) {
                const int mb = m0 + wm * 64 + i * 16 + quad * 4;
                #pragma unroll
                for (int rr = 0; rr < 4; ++rr)
                    ((float*)C)[(size_t)(mb + rr) * N + n] = acc[i][j][rr] + bv;
            }
        }
    }
}

// MFMA flash attention v7 (proven best: 49.0-49.6 us across R10/R11/R13).
// QT=128, 512 threads (8 waves x 16 q-rows), grid 512 = 2 blocks/CU. K/V
// staged by global_load_lds DMA with pre-swizzled per-lane global source
// addresses; waves 0-3 stage K, 4-7 stage V. P all-to-all via permlane;
// denominator via ones-MFMA; XCD head-affinity swizzle; exp2 w/ prescaled Q.
// Falsified alternatives (this session): PV-lag pipeline 51.8, 4-block QT64
// 53.0, 32x32 MFMA 53.2, counted-vmcnt depth-2 51.1 — the ~49 us floor is
// barrier-phase-latency structural, not pipe-bound (MfmaUtil 30/VALU 48).
__global__ __launch_bounds__(512, 4)
void attn_mfma7(const short* Q, const short* __restrict__ Kg,
                const short* __restrict__ Vt, short* O)
{
    // dispatch i -> XCD i&7 (round-robin). Give each XCD 4 (b,h) combos.
    const int i    = blockIdx.x;          // 512 blocks
    const int xcd  = i & 7;
    const int slot = i >> 3;              // 0..63
    const int combo = xcd * 4 + (slot >> 4);   // (b,h) 0..31
    const int qb = slot & 15;                  // 16 q-blocks per (b,h)
    const int h  = combo & 15;
    const int b  = combo >> 4;
    const int q0 = qb * QT;

    const int tid  = threadIdx.x;
    const int lane = tid & 63;
    const int wave = tid >> 6;            // 0..7
    const int quad = lane >> 4;
    const int l16  = lane & 15;
    const int l8   = l16 & 7;

    __shared__ __align__(16) short Ks[2][64 * 64];   // [key][d]   swizzled image
    __shared__ __align__(16) short Vs[2][64 * 64];   // [d][key]   swizzled image

    // Q B-frags (prescaled by 0.125*log2e): wave handles 16 q-rows
    s8v qf[2];
    #pragma unroll
    for (int kk = 0; kk < 2; ++kk)
        qf[kk] = *(const s8v*)(Q + (size_t)(b * SEQ + q0 + wave * 16 + l16) * EMB
                                 + h * DHEAD + kk * 32 + quad * 8);

    f4v oacc[4] = {};   // [j: d-block] -> O^T[d][q]
    f4v sacc    = {};   // ones-MFMA row sums (col = q, all rows equal)
    s8v onef;
    #pragma unroll
    for (int e = 0; e < 8; ++e) onef[e] = (short)0x3F80;   // bf16 1.0

    // ---- DMA staging setup: lane (r,c) covers row r, physical chunk c ----
    const int r = lane >> 3, c = lane & 7;
    const int sc8 = (c ^ r) * 8;               // pre-swizzled source chunk
    const bool isK = wave < 4;
    const int wrow = (wave & 3) * 16;          // 16 rows per stager wave
    const size_t kbase = (size_t)(b * SEQ) * EMB + h * DHEAD;
    const size_t vbase = (size_t)((b * NHEAD + h) * DHEAD) * SEQ;
    // per-lane global source for tile 0
    const short* gsrc = isK ? Kg + kbase + (size_t)(wrow + r) * EMB + sc8
                            : Vt + vbase + (size_t)(wrow + r) * SEQ + sc8;
    const size_t gstep8 = isK ? (size_t)8 * EMB : (size_t)8 * SEQ;  // +8 rows
    const size_t tstep  = isK ? (size_t)KT * EMB : (size_t)KT;      // +1 tile
    short* const lbase  = (isK ? (short*)Ks : (short*)Vs) + wrow * 64;

    // prologue: issue DMA for tile 0 into buf 0
    gl_lds16(gsrc,          lbase);
    gl_lds16(gsrc + gstep8, lbase + 8 * 64);
    const short* gnext = gsrc + tstep;

    for (int t = 0; t < NTILE; ++t) {
        const int buf = t & 1;
        __syncthreads();   // vmcnt(0)+barrier: tile t landed everywhere;
                           // compute(t-1) done everywhere -> buf^1 is free
        if (t + 1 < NTILE) {
            short* ldst = lbase + (buf ^ 1) * (64 * 64);
            gl_lds16(gnext,          ldst);
            gl_lds16(gnext + gstep8, ldst + 8 * 64);
            gnext += tstep;
        }
        const short* KsB = Ks[buf];
        const short* VsB = Vs[buf];

        // ---- S^T[key][q] = K · Q^T (already in log2 domain) ----
        f4v sc[4] = {};
        #pragma unroll
        for (int kk = 0; kk < 2; ++kk) {
            const int ko = ((kk * 4 + quad) ^ l8) * 8;
            s8v kf[4];
            #pragma unroll
            for (int j = 0; j < 4; ++j)
                kf[j] = *(const s8v*)(KsB + (j * 16 + l16) * 64 + ko);
            #pragma unroll
            for (int j = 0; j < 4; ++j)
                sc[j] = __builtin_amdgcn_mfma_f32_16x16x32_bf16(
                    kf[j], qf[kk], sc[j], 0, 0, 0);
        }

        // ---- p = 2^s, pack to bf16 pairs ----
        unsigned u[4][2];
        #pragma unroll
        for (int j = 0; j < 4; ++j) {
            u[j][0] = pk2(exp2_fast(sc[j][0]), exp2_fast(sc[j][1]));
            u[j][1] = pk2(exp2_fast(sc[j][2]), exp2_fast(sc[j][3]));
        }

        // ---- in-register all-to-all over lane bits 4/5 ----
        #pragma unroll
        for (int r2 = 0; r2 < 2; ++r2) {
            pl32swap(u[0][r2], u[1][r2]);   // stage A: b5' = j&1
            pl32swap(u[2][r2], u[3][r2]);
            pl16swap(u[0][r2], u[1][r2]);   // stage B: b4' = orig b5
            pl16swap(u[2][r2], u[3][r2]);
        }
        union { unsigned uu[4]; s8v s; } pfa, pfb;
        pfa.uu[0] = u[0][0]; pfa.uu[1] = u[0][1]; pfa.uu[2] = u[1][0]; pfa.uu[3] = u[1][1];
        pfb.uu[0] = u[2][0]; pfb.uu[1] = u[2][1]; pfb.uu[2] = u[3][0]; pfb.uu[3] = u[3][1];

        // ---- O^T[d][q] += V^T[d][key] · P^T ; row sums via ones-MFMA ----
        #pragma unroll
        for (int kk = 0; kk < 2; ++kk) {
            const s8v pf = kk ? pfb.s : pfa.s;
            sacc = __builtin_amdgcn_mfma_f32_16x16x32_bf16(onef, pf, sacc, 0, 0, 0);
            const int ko = ((kk * 4 + quad) ^ l8) * 8;
            #pragma unroll
            for (int j = 0; j < 4; ++j) {
                const s8v vf = *(const s8v*)(VsB + (j * 16 + l16) * 64 + ko);
                oacc[j] = __builtin_amdgcn_mfma_f32_16x16x32_bf16(
                    vf, pf, oacc[j], 0, 0, 0);
            }
        }
    }

    // ---- denominator: every row of sacc holds the full sum for col q ----
    const float inv = 1.0f / sacc[0];

    __syncthreads();   // everyone done with K/V LDS; reuse all of Ks as Os
    short* Os = (short*)Ks;   // 128 rows x 64 shorts = 16 KB
    #pragma unroll
    for (int j = 0; j < 4; ++j) {
        union { unsigned uu[2]; s4v s; } ov;
        ov.uu[0] = pk2(oacc[j][0] * inv, oacc[j][1] * inv);
        ov.uu[1] = pk2(oacc[j][2] * inv, oacc[j][3] * inv);
        const int pc = ((j * 2 + (quad >> 1)) ^ l8) * 8 + (quad & 1) * 4;
        *(s4v*)(Os + (wave * 16 + l16) * 64 + pc) = ov.s;
    }
    bar_lds();

    // ---- coalesced store: LDS swizzle cancels the output chunk swizzle ----
    const int row = tid >> 2;            // 0..127
    const int cb  = (tid & 3) * 2;       // two physical chunks per thread
    #pragma unroll
    for (int c4 = 0; c4 < 2; ++c4) {
        const int pcc = cb + c4;
        const s8v tt = *(const s8v*)(Os + row * 64 + pcc * 8);
        *(s8v*)(O + (size_t)(b * SEQ + q0 + row) * EMB + h * DHEAD + pcc * 8) = tt;
    }
}

extern "C" void kernel_launch(void* const* d_in, const int* in_sizes, int n_in,
                              void* d_out, int out_size, void* d_ws, size_t ws_size,
                              hipStream_t stream)
{
    const float* x  = (const float*)d_in[0];
    const float* Wq = (const float*)d_in[1];
    const float* bq = (const float*)d_in[2];
    const float* Wk = (const float*)d_in[3];
    const float* bk = (const float*)d_in[4];
    const float* Wv = (const float*)d_in[5];
    const float* bv = (const float*)d_in[6];
    const float* Wo = (const float*)d_in[7];
    const float* bo = (const float*)d_in[8];
    float* out = (float*)d_out;   // fp32 output

    short* xb  = (short*)d_ws;                       // 4096x1024 bf16, swizzled
    short* Wqb = xb  + (size_t)MTOT * EMB;           // swizzled
    short* Wkb = Wqb + (size_t)EMB * EMB;
    short* Wvb = Wkb + (size_t)EMB * EMB;
    short* Wob = Wvb + (size_t)EMB * EMB;
    short* Qw  = Wob + (size_t)EMB * EMB;            // [token][1024] (Q: plain;
                                                     //  then O: swizzled)
    short* Kw  = Qw  + (size_t)MTOT * EMB;           // [token][1024] plain
    short* Vtw = Kw  + (size_t)MTOT * EMB;           // [b][h][d][s] plain

    cvt_swz<<<dim3(512, 5), 256, 0, stream>>>(x, Wq, Wk, Wv, Wo,
                                              xb, Wqb, Wkb, Wvb, Wob);

    gemm_bb3<128, true><<<dim3(24, 32), 256, 0, stream>>>(
        xb, Wqb, Wkb, Wvb, bq, bk, bv, Qw, Kw, Vtw);

    attn_mfma7<<<dim3(BATCH * NHEAD * (SEQ / QT)), 512, 0, stream>>>(Qw, Kw, Vtw, Qw);

    gemm_bb3<64, false><<<dim3(16, 32), 256, 0, stream>>>(
        Qw, Wob, Wob, Wob, bo, bo, bo, out, out, out);
}